// Round 7
// baseline (617.273 us; speedup 1.0000x reference)
//
#include <hip/hip_runtime.h>
#include <hip/hip_bf16.h>

// GCN forward on MI355X.
// Pipeline (4 kernels): prep(quantize x->int8/row-scale | bucket scatter | pack W1,W2)
//   -> reorder2 (per-bucket row sort, 32 rows/bucket, int2 extents + raw-val 4B edges)
//   -> FUSED [SpMM1 int8 gather (scl via s_load) -> LDS tile -> MFMA GEMM1+ReLU -> MFMA proj -> g bf16]
//   -> fused SpMM2+bias+log_softmax over g.
// Algebra: spmm(A,h2)@W2 == spmm(A, h2@W2); h1 and h2 never hit global memory.
// Staged word (bcv): bits[16:0]=col, bits[21:17]=row&31, bits[28:22]=val q7 (val~q/128).
// Edge word: bits[16:0]=col, bits[31:17]=top-15 fp32 bits of q/128 (exact, e8m6).
// R1: Phase-A gather scalar-broadcast: v_readlane -> SGPR decode -> SGPR-base loads, groups of 8.
// R2: x int8 + per-row scale (256B/row). Gather request/byte-rate capped (~0.157 lines/cyc/CU);
//     spmm = 97% of that floor.
// R3: head reads 16B bf16 g rows: 1 line-request per edge.
// R4/R5: scl[col] applied in spmm Phase A via uniform s_load (scalar port) + 1 v_mul/edge.
// R6 LESSON: global per-row 4B scatter = 192MB partial-line writebacks (15x amplification).
//     Random small writes are only safe into bucket regions whose lines fill monotonically in
//     time (slot counter), so they complete while L2-resident.
// R7: build = one-pass GLOBAL-atomic bucket scatter (no LDS machine; 3125 buckets x 32 rows,
//     BCAP=1280=+8sigma, monotone slot fill) fused into prep + lightweight reorder2 (3125
//     blocks, 32-counter hist, register-staged edges, one bcv read).

constexpr int N_NODES = 100000;
constexpr int N_EDGES = 3200000;
constexpr int D = 256;
constexpr int NCLS = 8;

constexpr int NBUCK = 3125;    // bucket = row >> 5 (32 rows/bucket); 3125*32 == N_NODES
constexpr int BCAP  = 1280;    // padded bucket capacity (E[fill]=1024, sigma=32, +8sigma)

constexpr int CVT_BLOCKS  = N_NODES / 4;               // 25000 (4 rows/block, 1 row/wave)
constexpr int SCT_BLOCKS  = N_EDGES / 256;             // 12500
constexpr int PACK_BLOCKS = D * D / 256;               // 256 (W1) ; +1 block for W2

typedef __attribute__((ext_vector_type(8))) short bf16x8;
typedef __attribute__((ext_vector_type(4))) float f32x4;

__device__ inline unsigned short f2bf(float f) {
    __hip_bfloat16 h = __float2bfloat16(f);   // RNE
    return __builtin_bit_cast(unsigned short, h);
}
__device__ inline float bflo(unsigned u) { return __uint_as_float(u << 16); }
__device__ inline float bfhi(unsigned u) { return __uint_as_float(u & 0xffff0000u); }

// ---------------- prep: int8 quant | bucket scatter | w1_pack | w2_pack ----------------

__global__ __launch_bounds__(256) void prep_kernel(const float* __restrict__ x,
                                                   unsigned char* __restrict__ x8,
                                                   float* __restrict__ scl,
                                                   const int* __restrict__ row,
                                                   const int* __restrict__ col,
                                                   const float* __restrict__ val,
                                                   int* __restrict__ bucket_fill,
                                                   int* __restrict__ bcv,
                                                   const float* __restrict__ W1,
                                                   unsigned short* __restrict__ w1p,
                                                   const float* __restrict__ W2,
                                                   unsigned short* __restrict__ w2p) {
    const int bid = blockIdx.x;
    const int t = threadIdx.x;
    if (bid < CVT_BLOCKS) {
        // one row per wave: lane l covers features [4l, 4l+4)
        const int wave = t >> 6;
        const int lane = t & 63;
        const int r = bid * 4 + wave;
        const float4 v = ((const float4*)x)[r * 64 + lane];
        float am = fmaxf(fmaxf(fabsf(v.x), fabsf(v.y)), fmaxf(fabsf(v.z), fabsf(v.w)));
        #pragma unroll
        for (int o = 32; o > 0; o >>= 1) am = fmaxf(am, __shfl_xor(am, o));
        am = fmaxf(am, 1e-20f);
        const float inv = 127.f / am;
        const int q0 = (int)rintf(v.x * inv);
        const int q1 = (int)rintf(v.y * inv);
        const int q2 = (int)rintf(v.z * inv);
        const int q3 = (int)rintf(v.w * inv);
        const unsigned pk = (unsigned)(q0 & 255) | ((unsigned)(q1 & 255) << 8) |
                            ((unsigned)(q2 & 255) << 16) | ((unsigned)(q3 & 255) << 24);
        ((unsigned*)x8)[r * 64 + lane] = pk;
        if (lane == 0) scl[r] = am * (1.f / 127.f);
    } else if (bid < CVT_BLOCKS + SCT_BLOCKS) {
        // ---- bucket scatter: one edge per thread, global atomic slot alloc ----
        const int i = (bid - CVT_BLOCKS) * 256 + t;
        const int r = row[i];
        const unsigned q = (unsigned)__builtin_fminf(val[i] * 128.f + 0.5f, 127.f);
        const int word = col[i] | ((r & 31) << 17) | (int)(q << 22);
        const int b = r >> 5;
        const int slot = atomicAdd(&bucket_fill[b], 1);
        bcv[b * BCAP + slot] = word;
    } else if (bid < CVT_BLOCKS + SCT_BLOCKS + PACK_BLOCKS) {
        int idx = (bid - CVT_BLOCKS - SCT_BLOCKS) * 256 + t;
        int j = idx & 7, lane = (idx >> 3) & 63, s = (idx >> 9) & 7, nt = idx >> 12;
        int k = s * 32 + (lane >> 4) * 8 + j;
        int n = nt * 16 + (lane & 15);
        w1p[idx] = f2bf(W1[k * D + n]);
    } else {
        // W2 B-frag pack: 8 k-steps x 64 lanes x 8 j (n>=8 zero-padded)
        for (int i = t; i < 8 * 64 * 8; i += 256) {
            int j = i & 7, lane = (i >> 3) & 63, s = i >> 9;
            int k = s * 32 + ((lane >> 4)) * 8 + j;
            int n = lane & 15;
            w2p[i] = (n < NCLS) ? f2bf(W2[k * NCLS + n]) : (unsigned short)0;
        }
    }
}

// ---------------- reorder2: per-bucket row sort (32 rows), register-staged, one bcv read ------
// Emits int2 row extents and edge words (col | top-15 fp32 bits of q/128).

__global__ __launch_bounds__(256) void reorder_kernel(const int* __restrict__ bucket_fill,
                                                      const int* __restrict__ bcv,
                                                      int2* __restrict__ offs2,
                                                      int* __restrict__ edges) {
    __shared__ int rh[32];
    __shared__ int cur[32];
    const int b = blockIdx.x;
    const int t = threadIdx.x;
    const int base = b * BCAP;
    const int cnt  = bucket_fill[b];

    if (t < 32) rh[t] = 0;
    __syncthreads();

    // register-stage this thread's edges (<=5: BCAP/256 = 5) + histogram
    unsigned w[5];
    #pragma unroll
    for (int k = 0; k < 5; k++) {
        const int i = t + k * 256;
        if (i < cnt) {
            w[k] = (unsigned)bcv[base + i];
            atomicAdd(&rh[(w[k] >> 17) & 31], 1);
        }
    }
    __syncthreads();
    const int myc = (t < 32) ? rh[t] : 0;
    __syncthreads();
    if (t == 0) {
        int run = 0;
        #pragma unroll
        for (int i = 0; i < 32; i++) { int c = rh[i]; rh[i] = run; run += c; }
    }
    __syncthreads();
    if (t < 32) {
        const int excl = rh[t];
        offs2[(b << 5) + t] = make_int2(base + excl, base + excl + myc);
        cur[t] = base + excl;
    }
    __syncthreads();
    #pragma unroll
    for (int k = 0; k < 5; k++) {
        const int i = t + k * 256;
        if (i < cnt) {
            const unsigned wrd = w[k];
            const int r5 = (wrd >> 17) & 31;
            const int p = atomicAdd(&cur[r5], 1);
            const float f = (float)((wrd >> 22) & 127u) * 0.0078125f;  // q/128 exact (<=6 mant bits)
            edges[p] = (int)((__float_as_uint(f) & 0xFFFE0000u) | (wrd & 0x1FFFFu));
        }
    }
}

// ---------------- FUSED: SpMM1 int8 gather -> LDS tile -> MFMA GEMM1+ReLU -> MFMA proj ----------------
// 32 nodes/block (100000 = 3125*32 exact), 4 waves. Phase A: wave gathers 8 nodes
// (wave-per-node loop, lane l covers features [4l,4l+4) = one dword of int8). Edge words
// broadcast to SGPRs via v_readlane; per-edge scl[c] is a uniform (scalar-port) load folded
// with one v_mul. 8 independent dword loads in flight per group.
// Phase B: 32x256 MFMA GEMM from LDS tile + packed W1, bias+relu back into tile.
// Phase C: MFMA proj -> raw g stored bf16 (16 B/row).

constexpr int SCPITCH = 264;   // shorts; 528B rows, 16B-aligned

__global__ __launch_bounds__(256) void spmm_gemm_proj_kernel(const int2* __restrict__ offs2,
                                                             const int* __restrict__ edges,
                                                             const unsigned char* __restrict__ x8,
                                                             const float* __restrict__ scl,
                                                             const unsigned short* __restrict__ w1p,
                                                             const float* __restrict__ b1,
                                                             const unsigned short* __restrict__ w2p,
                                                             unsigned short* __restrict__ g2) {
    __shared__ unsigned short sC[32 * SCPITCH];   // 16.5 KB

    const int tid  = threadIdx.x;
    const int wave = tid >> 6;
    const int lane = tid & 63;
    const int quad = lane >> 4;
    const int l15  = lane & 15;
    const int row0 = blockIdx.x * 32;

    // ---- Phase A: gather-SpMM, 8 nodes per wave (scalar-broadcast edges, int8 rows) ----
    int2 se = make_int2(0, 0);
    if (lane < 8) se = offs2[row0 + wave * 8 + lane];

    for (int idx = 0; idx < 8; idx++) {
        const int s = __builtin_amdgcn_readlane(se.x, idx);
        const int e = __builtin_amdgcn_readlane(se.y, idx);
        float4 acc = make_float4(0.f, 0.f, 0.f, 0.f);

        for (int base = s; base < e; base += 64) {
            const int rem = e - base;
            int ed = 0;                                // col 0, val +0.0 -> contributes 0
            if (lane < rem) ed = edges[base + lane];
            const int cnt = rem < 64 ? rem : 64;
            // groups of 8; tail group zero-padded via ed==0 lanes (adds exactly 0)
            for (int gb = 0; gb < cnt; gb += 8) {
                unsigned wv[8]; unsigned p[8]; float sv[8];
                #pragma unroll
                for (int u = 0; u < 8; u++)
                    wv[u] = (unsigned)__builtin_amdgcn_readlane(ed, gb + u);
                #pragma unroll
                for (int u = 0; u < 8; u++) {
                    const unsigned c = wv[u] & 0x1FFFFu;   // uniform -> SGPR
                    sv[u] = scl[c];                        // uniform -> s_load (scalar port)
                    p[u] = *((const unsigned*)(x8 + ((size_t)c << 8)) + lane);
                }
                #pragma unroll
                for (int u = 0; u < 8; u++) {
                    const float v = __uint_as_float(wv[u] & 0xFFFE0000u) * sv[u];
                    const unsigned pk = p[u];
                    acc.x = fmaf(v, (float)((int)(pk << 24) >> 24), acc.x);
                    acc.y = fmaf(v, (float)((int)(pk << 16) >> 24), acc.y);
                    acc.z = fmaf(v, (float)((int)(pk <<  8) >> 24), acc.z);
                    acc.w = fmaf(v, (float)((int)pk >> 24),         acc.w);
                }
            }
        }
        const int rl = wave * 8 + idx;
        ushort4 o;
        o.x = f2bf(acc.x); o.y = f2bf(acc.y); o.z = f2bf(acc.z); o.w = f2bf(acc.w);
        *(ushort4*)&sC[rl * SCPITCH + lane * 4] = o;
    }
    __syncthreads();

    // ---- Phase B: MFMA GEMM (32 x 256) ----
    const int ntb = wave * 4;
    f32x4 acc[2][4] = {};   // [mt][nt]

    #pragma unroll
    for (int s = 0; s < 8; s++) {
        bf16x8 a[2], b[4];
        #pragma unroll
        for (int mt = 0; mt < 2; mt++)
            a[mt] = __builtin_bit_cast(bf16x8,
                *(const uint4*)&sC[(mt * 16 + l15) * SCPITCH + s * 32 + quad * 8]);
        #pragma unroll
        for (int nt = 0; nt < 4; nt++)
            b[nt] = __builtin_bit_cast(bf16x8,
                *(const uint4*)(w1p + (((size_t)(ntb + nt) * 8 + s) * 64 + lane) * 8));
        #pragma unroll
        for (int mt = 0; mt < 2; mt++)
            #pragma unroll
            for (int nt = 0; nt < 4; nt++)
                acc[mt][nt] = __builtin_amdgcn_mfma_f32_16x16x32_bf16(a[mt], b[nt], acc[mt][nt], 0, 0, 0);
    }
    __syncthreads();   // all tile reads done before overwrite

    // bias + relu -> back into sC
    #pragma unroll
    for (int nt = 0; nt < 4; nt++) {
        const int n = (ntb + nt) * 16 + l15;
        const float bias = b1[n];
        #pragma unroll
        for (int mt = 0; mt < 2; mt++) {
            #pragma unroll
            for (int i = 0; i < 4; i++) {
                const int rl = mt * 16 + quad * 4 + i;
                float v = acc[mt][nt][i] + bias;
                sC[rl * SCPITCH + n] = f2bf(v > 0.f ? v : 0.f);
            }
        }
    }
    __syncthreads();

    // ---- Phase C: proj via MFMA (waves 0,1 cover the 2 row-tiles); store raw g as bf16 ----
    if (wave < 2) {
        f32x4 pacc = {};
        #pragma unroll
        for (int s = 0; s < 8; s++) {
            bf16x8 a = __builtin_bit_cast(bf16x8,
                *(const uint4*)&sC[(wave * 16 + l15) * SCPITCH + s * 32 + quad * 8]);
            bf16x8 b = __builtin_bit_cast(bf16x8,
                *(const uint4*)(w2p + ((size_t)s * 64 + lane) * 8));
            pacc = __builtin_amdgcn_mfma_f32_16x16x32_bf16(a, b, pacc, 0, 0, 0);
        }
        if (l15 < NCLS) {
            #pragma unroll
            for (int i = 0; i < 4; i++) {
                const int grow = row0 + wave * 16 + quad * 4 + i;
                g2[(size_t)grow * NCLS + l15] = f2bf(pacc[i]);
            }
        }
    }
}

// ---------------- fused SpMM2 (8-wide) + bias + log_softmax, half-wave per node ----------------
// Raw edges (q/128) against raw bf16 g rows: one 16B load per edge.

__global__ __launch_bounds__(256) void head_spmm_kernel(const int2* __restrict__ offs2,
                                                        const int* __restrict__ edges,
                                                        const unsigned short* __restrict__ g2,
                                                        const float* __restrict__ b2,
                                                        float* __restrict__ out) {
    const int tid  = threadIdx.x;
    const int hw   = tid >> 5;
    const int hl   = tid & 31;
    const int node = blockIdx.x * 8 + hw;
    if (node >= N_NODES) return;

    const int2 se = offs2[node];
    const int s = se.x;
    const int e = se.y;

    float acc[NCLS] = {};
    for (int base = s; base < e; base += 32) {
        const int rem = e - base;
        if (hl < rem) {
            const unsigned w = (unsigned)edges[base + hl];
            const int   c = (int)(w & 0x1FFFFu);
            const float v = __uint_as_float(w & 0xFFFE0000u);
            const uint4 q = *((const uint4*)g2 + c);   // 8 bf16 = 16 B
            acc[0] = fmaf(v, bflo(q.x), acc[0]); acc[1] = fmaf(v, bfhi(q.x), acc[1]);
            acc[2] = fmaf(v, bflo(q.y), acc[2]); acc[3] = fmaf(v, bfhi(q.y), acc[3]);
            acc[4] = fmaf(v, bflo(q.z), acc[4]); acc[5] = fmaf(v, bfhi(q.z), acc[5]);
            acc[6] = fmaf(v, bflo(q.w), acc[6]); acc[7] = fmaf(v, bfhi(q.w), acc[7]);
        }
    }
    #pragma unroll
    for (int c = 0; c < NCLS; c++) {
        #pragma unroll
        for (int o = 16; o > 0; o >>= 1) acc[c] += __shfl_xor(acc[c], o);
    }

    float logits[NCLS];
    #pragma unroll
    for (int c = 0; c < NCLS; c++) logits[c] = acc[c] + b2[c];
    float m = logits[0];
    #pragma unroll
    for (int c = 1; c < NCLS; c++) m = fmaxf(m, logits[c]);
    float sum = 0.f;
    #pragma unroll
    for (int c = 0; c < NCLS; c++) sum += __expf(logits[c] - m);
    const float lse = m + __logf(sum);
    if (hl < NCLS) out[(size_t)node * NCLS + hl] = logits[hl] - lse;
}

// ---------------- launcher ----------------

extern "C" void kernel_launch(void* const* d_in, const int* in_sizes, int n_in,
                              void* d_out, int out_size, void* d_ws, size_t ws_size,
                              hipStream_t stream) {
    const float* x       = (const float*)d_in[0];
    const int*   adj_row = (const int*)  d_in[1];
    const int*   adj_col = (const int*)  d_in[2];
    const float* adj_val = (const float*)d_in[3];
    const float* W1      = (const float*)d_in[4];
    const float* b1      = (const float*)d_in[5];
    const float* W2      = (const float*)d_in[6];
    const float* b2      = (const float*)d_in[7];
    float* out = (float*)d_out;

    char* w = (char*)d_ws;
    auto alloc = [&](size_t bytes) -> char* {
        char* p = w;
        w += (bytes + 255) & ~(size_t)255;
        return p;
    };
    int*            bucket_fill = (int*)  alloc((size_t)NBUCK * 4);
    int2*           offs2       = (int2*) alloc((size_t)N_NODES * 8);
    int*            bcv         = (int*)  alloc((size_t)NBUCK * BCAP * 4);
    int*            edges       = (int*)  alloc((size_t)NBUCK * BCAP * 4);
    unsigned char*  x8          = (unsigned char*)alloc((size_t)N_NODES * D);
    float*          scl         = (float*)alloc((size_t)N_NODES * 4);
    unsigned short* w1p         = (unsigned short*)alloc((size_t)D * D * 2);
    unsigned short* w2p         = (unsigned short*)alloc((size_t)8 * 64 * 8 * 2);
    unsigned short* g2          = (unsigned short*)alloc((size_t)N_NODES * NCLS * 2);

    hipMemsetAsync(bucket_fill, 0, (size_t)NBUCK * 4, stream);

    prep_kernel<<<CVT_BLOCKS + SCT_BLOCKS + PACK_BLOCKS + 1, 256, 0, stream>>>(
        x, x8, scl, adj_row, adj_col, adj_val, bucket_fill, bcv, W1, w1p, W2, w2p);

    reorder_kernel<<<NBUCK, 256, 0, stream>>>(bucket_fill, bcv, offs2, edges);

    spmm_gemm_proj_kernel<<<N_NODES / 32, 256, 0, stream>>>(
        offs2, edges, x8, scl, w1p, b1, w2p, g2);

    const int nb8 = (N_NODES + 7) / 8;
    head_spmm_kernel<<<nb8, 256, 0, stream>>>(offs2, edges, g2, b2, out);
}

// Round 8
// 382.758 us; speedup vs baseline: 1.6127x; 1.6127x over previous
//
#include <hip/hip_runtime.h>
#include <hip/hip_bf16.h>

// GCN forward on MI355X.
// Pipeline (5 kernels): prep(quantize x->int8/row-scale | pack W1,W2) -> bin_scatter (LDS binning
//   into padded buckets, single-CU chunk copy-out) -> reorder (register-staged, one bcv read)
//   -> FUSED [SpMM1 int8 gather (scl via s_load) -> LDS tile -> MFMA GEMM1+ReLU -> MFMA proj -> g bf16]
//   -> fused SpMM2+bias+log_softmax over g.
// Algebra: spmm(A,h2)@W2 == spmm(A, h2@W2); h1 and h2 never hit global memory.
// Staged word (bcv): bits[16:0]=col, bits[24:17]=row&255, bits[31:25]=val q7 (val~q/128).
// Edge word: bits[16:0]=col, bits[31:17]=top-15 fp32 bits of q/128 (exact, e8m6).
// R1: Phase-A gather scalar-broadcast: v_readlane -> SGPR decode -> SGPR-base loads, groups of 8.
// R2: x int8 + per-row scale (256B/row). Gather request/byte-rate capped (~0.157 lines/cyc/CU);
//     spmm = 97% of that floor.
// R3: head reads 16B bf16 g rows: 1 line-request per edge.
// R4/R5: scl[col] applied in spmm Phase A via uniform s_load (scalar port) + 1 v_mul/edge;
//     count pass + scan kernel deleted via fixed-capacity padded buckets (BCAP=8704).
// R6/R7 LESSON (both failed, 15x write amplification): scattered 4B stores are only safe when
//     each 64B line is written by ONE CU in one burst (LDS-staged chunk copy-out). Global-atomic
//     slot allocators interleave CUs/XCDs onto the same line -> per-XCD partial writebacks
//     (per-XCD L2s not coherent). Build therefore stays LDS-staged two-phase.
// R8: revert to R5 structure; reorder register-stages its <=9 words (one bcv read, was two).

constexpr int N_NODES = 100000;
constexpr int N_EDGES = 3200000;
constexpr int D = 256;
constexpr int NCLS = 8;

constexpr int NBUCK  = 391;    // bucket = row >> 8 (256 rows/bucket)
constexpr int BCAP   = 8704;   // padded bucket capacity (E[cnt]=8192, sigma~90)
constexpr int BCHUNK = 6400;   // edges per binning block; 500 * 6400 == N_EDGES
constexpr int EPT    = BCHUNK / 256;

constexpr int CVT_BLOCKS  = N_NODES / 4;               // 25000 (4 rows/block, 1 row/wave)
constexpr int PACK_BLOCKS = D * D / 256;               // 256 (W1) ; +1 block for W2

typedef __attribute__((ext_vector_type(8))) short bf16x8;
typedef __attribute__((ext_vector_type(4))) float f32x4;

__device__ inline unsigned short f2bf(float f) {
    __hip_bfloat16 h = __float2bfloat16(f);   // RNE
    return __builtin_bit_cast(unsigned short, h);
}
__device__ inline float bflo(unsigned u) { return __uint_as_float(u << 16); }
__device__ inline float bfhi(unsigned u) { return __uint_as_float(u & 0xffff0000u); }

// ---------------- prep: int8 quant | w1_pack | w2_pack ----------------

__global__ __launch_bounds__(256) void prep_kernel(const float* __restrict__ x,
                                                   unsigned char* __restrict__ x8,
                                                   float* __restrict__ scl,
                                                   const float* __restrict__ W1,
                                                   unsigned short* __restrict__ w1p,
                                                   const float* __restrict__ W2,
                                                   unsigned short* __restrict__ w2p) {
    const int bid = blockIdx.x;
    const int t = threadIdx.x;
    if (bid < CVT_BLOCKS) {
        // one row per wave: lane l covers features [4l, 4l+4)
        const int wave = t >> 6;
        const int lane = t & 63;
        const int r = bid * 4 + wave;
        const float4 v = ((const float4*)x)[r * 64 + lane];
        float am = fmaxf(fmaxf(fabsf(v.x), fabsf(v.y)), fmaxf(fabsf(v.z), fabsf(v.w)));
        #pragma unroll
        for (int o = 32; o > 0; o >>= 1) am = fmaxf(am, __shfl_xor(am, o));
        am = fmaxf(am, 1e-20f);
        const float inv = 127.f / am;
        const int q0 = (int)rintf(v.x * inv);
        const int q1 = (int)rintf(v.y * inv);
        const int q2 = (int)rintf(v.z * inv);
        const int q3 = (int)rintf(v.w * inv);
        const unsigned pk = (unsigned)(q0 & 255) | ((unsigned)(q1 & 255) << 8) |
                            ((unsigned)(q2 & 255) << 16) | ((unsigned)(q3 & 255) << 24);
        ((unsigned*)x8)[r * 64 + lane] = pk;
        if (lane == 0) scl[r] = am * (1.f / 127.f);
    } else if (bid < CVT_BLOCKS + PACK_BLOCKS) {
        int idx = (bid - CVT_BLOCKS) * 256 + t;
        int j = idx & 7, lane = (idx >> 3) & 63, s = (idx >> 9) & 7, nt = idx >> 12;
        int k = s * 32 + (lane >> 4) * 8 + j;
        int n = nt * 16 + (lane & 15);
        w1p[idx] = f2bf(W1[k * D + n]);
    } else {
        // W2 B-frag pack: 8 k-steps x 64 lanes x 8 j (n>=8 zero-padded)
        for (int i = t; i < 8 * 64 * 8; i += 256) {
            int j = i & 7, lane = (i >> 3) & 63, s = i >> 9;
            int k = s * 32 + ((lane >> 4)) * 8 + j;
            int n = lane & 15;
            w2p[i] = (n < NCLS) ? f2bf(W2[k * NCLS + n]) : (unsigned short)0;
        }
    }
}

// ---------------- binning: LDS-staged scatter into padded bucket regions ----------------
// Chunk copy-out keeps each 64B line single-CU-written (R6/R7 lesson).

__global__ __launch_bounds__(256) void bin_scatter_kernel(const int* __restrict__ row,
                                                          const int* __restrict__ col,
                                                          const float* __restrict__ val,
                                                          int* __restrict__ bucket_fill,
                                                          int* __restrict__ bcv) {
    __shared__ int s_cv[BCHUNK];             // 25600 B
    __shared__ unsigned short s_bk[BCHUNK];  // 12800 B
    __shared__ int s_h[512];                 //  2048 B (hist -> inclusive scan)
    __shared__ int s_base[512];              //  2048 B (global base - excl)
    __shared__ int s_cur[NBUCK];             //  1564 B
    const int t = threadIdx.x;
    const int base = blockIdx.x * BCHUNK + t;

    int rl[EPT]; int cvl[EPT];
    #pragma unroll
    for (int j = 0; j < EPT; j++) {
        int i = base + j * 256;
        int r = row[i];
        rl[j] = r;
        // q7 = round(val*128) clamped to 127; val in [0,1)
        unsigned q = (unsigned)__builtin_fminf(val[i] * 128.f + 0.5f, 127.f);
        cvl[j] = col[i] | ((r & 255) << 17) | (int)(q << 25);
    }
    s_h[t] = 0; s_h[t + 256] = 0;
    __syncthreads();
    #pragma unroll
    for (int j = 0; j < EPT; j++) atomicAdd(&s_h[rl[j] >> 8], 1);
    __syncthreads();
    int c0 = s_h[t], c1 = s_h[t + 256];
    for (int o = 1; o < 512; o <<= 1) {
        int v0 = (t >= o) ? s_h[t - o] : 0;
        int v1 = (t + 256 >= o) ? s_h[t + 256 - o] : 0;
        __syncthreads();
        s_h[t] += v0; s_h[t + 256] += v1;
        __syncthreads();
    }
    const int e0 = s_h[t] - c0;
    const int e1 = s_h[t + 256] - c1;
    if (t < NBUCK) s_cur[t] = e0;
    if (t + 256 < NBUCK) s_cur[t + 256] = e1;
    __syncthreads();
    #pragma unroll
    for (int j = 0; j < EPT; j++) {
        int b = rl[j] >> 8;
        int q = atomicAdd(&s_cur[b], 1);
        s_cv[q] = cvl[j];
        s_bk[q] = (unsigned short)b;
    }
    if (t < NBUCK)
        s_base[t] = (c0 > 0 ? atomicAdd(&bucket_fill[t], c0) + t * BCAP : 0) - e0;
    if (t + 256 < NBUCK)
        s_base[t + 256] = (c1 > 0 ? atomicAdd(&bucket_fill[t + 256], c1) + (t + 256) * BCAP : 0) - e1;
    __syncthreads();
    for (int i = t; i < BCHUNK; i += 256) {
        bcv[s_base[s_bk[i]] + i] = s_cv[i];
    }
}

// ---------------- reorder: per-bucket row sort, register-staged (ONE bcv read) ----------
// Emits int2 row extents and edge words (col | top-15 fp32 bits of q/128).

__global__ __launch_bounds__(1024) void reorder_kernel(const int* __restrict__ bucket_fill,
                                                       const int* __restrict__ bcv,
                                                       int2* __restrict__ offs2,
                                                       int* __restrict__ edges) {
    __shared__ int rh[256];
    __shared__ int cur[256];
    const int b = blockIdx.x;
    const int t = threadIdx.x;
    const int base = b * BCAP;
    const int cnt  = bucket_fill[b];

    if (t < 256) rh[t] = 0;
    __syncthreads();

    // register-stage this thread's words (<= ceil(8704/1024) = 9) + histogram
    unsigned wl[9];
    #pragma unroll
    for (int k = 0; k < 9; k++) {
        const int i = t + k * 1024;
        if (i < cnt) {
            wl[k] = (unsigned)bcv[base + i];
            atomicAdd(&rh[(wl[k] >> 17) & 255], 1);
        }
    }
    __syncthreads();
    const int myc = (t < 256) ? rh[t] : 0;
    for (int o = 1; o < 256; o <<= 1) {
        int v = (t < 256 && t >= o) ? rh[t - o] : 0;
        __syncthreads();
        if (t < 256) rh[t] += v;
        __syncthreads();
    }
    if (t < 256) {
        const int incl = rh[t];
        const int excl = incl - myc;
        const int grow = (b << 8) + t;
        if (grow < N_NODES) offs2[grow] = make_int2(base + excl, base + incl);
        cur[t] = base + excl;
    }
    __syncthreads();
    #pragma unroll
    for (int k = 0; k < 9; k++) {
        const int i = t + k * 1024;
        if (i < cnt) {
            const unsigned wrd = wl[k];
            const int r8 = (wrd >> 17) & 255;
            const int p = atomicAdd(&cur[r8], 1);
            const float f = (float)(wrd >> 25) * 0.0078125f;   // q/128, <=6 mantissa bits -> exact
            edges[p] = (int)((__float_as_uint(f) & 0xFFFE0000u) | (wrd & 0x1FFFFu));
        }
    }
}

// ---------------- FUSED: SpMM1 int8 gather -> LDS tile -> MFMA GEMM1+ReLU -> MFMA proj ----------------
// 32 nodes/block (100000 = 3125*32 exact), 4 waves. Phase A: wave gathers 8 nodes
// (wave-per-node loop, lane l covers features [4l,4l+4) = one dword of int8). Edge words
// broadcast to SGPRs via v_readlane; per-edge scl[c] is a uniform (scalar-port) load folded
// with one v_mul. 8 independent dword loads in flight per group.
// Phase B: 32x256 MFMA GEMM from LDS tile + packed W1, bias+relu back into tile.
// Phase C: MFMA proj -> raw g stored bf16 (16 B/row).

constexpr int SCPITCH = 264;   // shorts; 528B rows, 16B-aligned

__global__ __launch_bounds__(256) void spmm_gemm_proj_kernel(const int2* __restrict__ offs2,
                                                             const int* __restrict__ edges,
                                                             const unsigned char* __restrict__ x8,
                                                             const float* __restrict__ scl,
                                                             const unsigned short* __restrict__ w1p,
                                                             const float* __restrict__ b1,
                                                             const unsigned short* __restrict__ w2p,
                                                             unsigned short* __restrict__ g2) {
    __shared__ unsigned short sC[32 * SCPITCH];   // 16.5 KB

    const int tid  = threadIdx.x;
    const int wave = tid >> 6;
    const int lane = tid & 63;
    const int quad = lane >> 4;
    const int l15  = lane & 15;
    const int row0 = blockIdx.x * 32;

    // ---- Phase A: gather-SpMM, 8 nodes per wave (scalar-broadcast edges, int8 rows) ----
    int2 se = make_int2(0, 0);
    if (lane < 8) se = offs2[row0 + wave * 8 + lane];

    for (int idx = 0; idx < 8; idx++) {
        const int s = __builtin_amdgcn_readlane(se.x, idx);
        const int e = __builtin_amdgcn_readlane(se.y, idx);
        float4 acc = make_float4(0.f, 0.f, 0.f, 0.f);

        for (int base = s; base < e; base += 64) {
            const int rem = e - base;
            int ed = 0;                                // col 0, val +0.0 -> contributes 0
            if (lane < rem) ed = edges[base + lane];
            const int cnt = rem < 64 ? rem : 64;
            // groups of 8; tail group zero-padded via ed==0 lanes (adds exactly 0)
            for (int gb = 0; gb < cnt; gb += 8) {
                unsigned wv[8]; unsigned p[8]; float sv[8];
                #pragma unroll
                for (int u = 0; u < 8; u++)
                    wv[u] = (unsigned)__builtin_amdgcn_readlane(ed, gb + u);
                #pragma unroll
                for (int u = 0; u < 8; u++) {
                    const unsigned c = wv[u] & 0x1FFFFu;   // uniform -> SGPR
                    sv[u] = scl[c];                        // uniform -> s_load (scalar port)
                    p[u] = *((const unsigned*)(x8 + ((size_t)c << 8)) + lane);
                }
                #pragma unroll
                for (int u = 0; u < 8; u++) {
                    const float v = __uint_as_float(wv[u] & 0xFFFE0000u) * sv[u];
                    const unsigned pk = p[u];
                    acc.x = fmaf(v, (float)((int)(pk << 24) >> 24), acc.x);
                    acc.y = fmaf(v, (float)((int)(pk << 16) >> 24), acc.y);
                    acc.z = fmaf(v, (float)((int)(pk <<  8) >> 24), acc.z);
                    acc.w = fmaf(v, (float)((int)pk >> 24),         acc.w);
                }
            }
        }
        const int rl = wave * 8 + idx;
        ushort4 o;
        o.x = f2bf(acc.x); o.y = f2bf(acc.y); o.z = f2bf(acc.z); o.w = f2bf(acc.w);
        *(ushort4*)&sC[rl * SCPITCH + lane * 4] = o;
    }
    __syncthreads();

    // ---- Phase B: MFMA GEMM (32 x 256) ----
    const int ntb = wave * 4;
    f32x4 acc[2][4] = {};   // [mt][nt]

    #pragma unroll
    for (int s = 0; s < 8; s++) {
        bf16x8 a[2], b[4];
        #pragma unroll
        for (int mt = 0; mt < 2; mt++)
            a[mt] = __builtin_bit_cast(bf16x8,
                *(const uint4*)&sC[(mt * 16 + l15) * SCPITCH + s * 32 + quad * 8]);
        #pragma unroll
        for (int nt = 0; nt < 4; nt++)
            b[nt] = __builtin_bit_cast(bf16x8,
                *(const uint4*)(w1p + (((size_t)(ntb + nt) * 8 + s) * 64 + lane) * 8));
        #pragma unroll
        for (int mt = 0; mt < 2; mt++)
            #pragma unroll
            for (int nt = 0; nt < 4; nt++)
                acc[mt][nt] = __builtin_amdgcn_mfma_f32_16x16x32_bf16(a[mt], b[nt], acc[mt][nt], 0, 0, 0);
    }
    __syncthreads();   // all tile reads done before overwrite

    // bias + relu -> back into sC
    #pragma unroll
    for (int nt = 0; nt < 4; nt++) {
        const int n = (ntb + nt) * 16 + l15;
        const float bias = b1[n];
        #pragma unroll
        for (int mt = 0; mt < 2; mt++) {
            #pragma unroll
            for (int i = 0; i < 4; i++) {
                const int rl = mt * 16 + quad * 4 + i;
                float v = acc[mt][nt][i] + bias;
                sC[rl * SCPITCH + n] = f2bf(v > 0.f ? v : 0.f);
            }
        }
    }
    __syncthreads();

    // ---- Phase C: proj via MFMA (waves 0,1 cover the 2 row-tiles); store raw g as bf16 ----
    if (wave < 2) {
        f32x4 pacc = {};
        #pragma unroll
        for (int s = 0; s < 8; s++) {
            bf16x8 a = __builtin_bit_cast(bf16x8,
                *(const uint4*)&sC[(wave * 16 + l15) * SCPITCH + s * 32 + quad * 8]);
            bf16x8 b = __builtin_bit_cast(bf16x8,
                *(const uint4*)(w2p + ((size_t)s * 64 + lane) * 8));
            pacc = __builtin_amdgcn_mfma_f32_16x16x32_bf16(a, b, pacc, 0, 0, 0);
        }
        if (l15 < NCLS) {
            #pragma unroll
            for (int i = 0; i < 4; i++) {
                const int grow = row0 + wave * 16 + quad * 4 + i;
                g2[(size_t)grow * NCLS + l15] = f2bf(pacc[i]);
            }
        }
    }
}

// ---------------- fused SpMM2 (8-wide) + bias + log_softmax, half-wave per node ----------------
// Raw edges (q/128) against raw bf16 g rows: one 16B load per edge.

__global__ __launch_bounds__(256) void head_spmm_kernel(const int2* __restrict__ offs2,
                                                        const int* __restrict__ edges,
                                                        const unsigned short* __restrict__ g2,
                                                        const float* __restrict__ b2,
                                                        float* __restrict__ out) {
    const int tid  = threadIdx.x;
    const int hw   = tid >> 5;
    const int hl   = tid & 31;
    const int node = blockIdx.x * 8 + hw;
    if (node >= N_NODES) return;

    const int2 se = offs2[node];
    const int s = se.x;
    const int e = se.y;

    float acc[NCLS] = {};
    for (int base = s; base < e; base += 32) {
        const int rem = e - base;
        if (hl < rem) {
            const unsigned w = (unsigned)edges[base + hl];
            const int   c = (int)(w & 0x1FFFFu);
            const float v = __uint_as_float(w & 0xFFFE0000u);
            const uint4 q = *((const uint4*)g2 + c);   // 8 bf16 = 16 B
            acc[0] = fmaf(v, bflo(q.x), acc[0]); acc[1] = fmaf(v, bfhi(q.x), acc[1]);
            acc[2] = fmaf(v, bflo(q.y), acc[2]); acc[3] = fmaf(v, bfhi(q.y), acc[3]);
            acc[4] = fmaf(v, bflo(q.z), acc[4]); acc[5] = fmaf(v, bfhi(q.z), acc[5]);
            acc[6] = fmaf(v, bflo(q.w), acc[6]); acc[7] = fmaf(v, bfhi(q.w), acc[7]);
        }
    }
    #pragma unroll
    for (int c = 0; c < NCLS; c++) {
        #pragma unroll
        for (int o = 16; o > 0; o >>= 1) acc[c] += __shfl_xor(acc[c], o);
    }

    float logits[NCLS];
    #pragma unroll
    for (int c = 0; c < NCLS; c++) logits[c] = acc[c] + b2[c];
    float m = logits[0];
    #pragma unroll
    for (int c = 1; c < NCLS; c++) m = fmaxf(m, logits[c]);
    float sum = 0.f;
    #pragma unroll
    for (int c = 0; c < NCLS; c++) sum += __expf(logits[c] - m);
    const float lse = m + __logf(sum);
    if (hl < NCLS) out[(size_t)node * NCLS + hl] = logits[hl] - lse;
}

// ---------------- launcher ----------------

extern "C" void kernel_launch(void* const* d_in, const int* in_sizes, int n_in,
                              void* d_out, int out_size, void* d_ws, size_t ws_size,
                              hipStream_t stream) {
    const float* x       = (const float*)d_in[0];
    const int*   adj_row = (const int*)  d_in[1];
    const int*   adj_col = (const int*)  d_in[2];
    const float* adj_val = (const float*)d_in[3];
    const float* W1      = (const float*)d_in[4];
    const float* b1      = (const float*)d_in[5];
    const float* W2      = (const float*)d_in[6];
    const float* b2      = (const float*)d_in[7];
    float* out = (float*)d_out;

    char* w = (char*)d_ws;
    auto alloc = [&](size_t bytes) -> char* {
        char* p = w;
        w += (bytes + 255) & ~(size_t)255;
        return p;
    };
    int*            bucket_fill = (int*)  alloc((NBUCK + 1) * 4);
    int2*           offs2       = (int2*) alloc((size_t)N_NODES * 8);
    int*            bcv         = (int*)  alloc((size_t)NBUCK * BCAP * 4);
    int*            edges       = (int*)  alloc((size_t)NBUCK * BCAP * 4);
    unsigned char*  x8          = (unsigned char*)alloc((size_t)N_NODES * D);
    float*          scl         = (float*)alloc((size_t)N_NODES * 4);
    unsigned short* w1p         = (unsigned short*)alloc((size_t)D * D * 2);
    unsigned short* w2p         = (unsigned short*)alloc((size_t)8 * 64 * 8 * 2);
    unsigned short* g2          = (unsigned short*)alloc((size_t)N_NODES * NCLS * 2);

    hipMemsetAsync(bucket_fill, 0, (NBUCK + 1) * 4, stream);

    prep_kernel<<<CVT_BLOCKS + PACK_BLOCKS + 1, 256, 0, stream>>>(
        x, x8, scl, W1, w1p, W2, w2p);

    bin_scatter_kernel<<<N_EDGES / BCHUNK, 256, 0, stream>>>(
        adj_row, adj_col, adj_val, bucket_fill, bcv);

    reorder_kernel<<<NBUCK, 1024, 0, stream>>>(bucket_fill, bcv, offs2, edges);

    spmm_gemm_proj_kernel<<<N_NODES / 32, 256, 0, stream>>>(
        offs2, edges, x8, scl, w1p, b1, w2p, g2);

    const int nb8 = (N_NODES + 7) / 8;
    head_spmm_kernel<<<nb8, 256, 0, stream>>>(offs2, edges, g2, b2, out);
}